// Round 7
// baseline (567.179 us; speedup 1.0000x reference)
//
#include <hip/hip_runtime.h>
#include <hip/hip_bf16.h>
#include <cstdint>

// SimplifiedMambaSSM on MI355X (gfx950)
// B=8, T=4096, D_MODEL=1024, D_STATE=16. Rows M = B*T = 32768.
//
// Pipeline (R7: LN stats moved into K2's epilogue -- R6 showed the
// projection stage is latency-bound, not BW-bound (deleting 128MB of XG
// traffic saved ~0us). lnproj loses its serial phase-1 and is re-tiled
// 32 rows x 128 thr x 1024 blocks for 2x waves/CU):
//  K1 convert : x, W_gate, [W_delta;W_B;W_C] -> bf16 copies; +64 blocks
//               zero the LN-stats array (first 256KB of hsb -- dead until
//               the scan overwrites it, after lnproj consumed it).
//  K2 gemm    : G = Xb @ Wgb^T (bf16 MFMA, 128x128 tiles, XCD-swizzled).
//               Epilogue: per row, partial {sum(v), sum(v^2)} of
//               v = G_f32 + bg over the wave's 64-col slice (shfl_xor
//               reduce over lrow, 2 atomicAdds from lane lrow==0).
//  K34 lnproj : 32-row tiles, 1024 blocks x 128 thr. Reads stats (no
//               phase 1), computes xg = sigmoid(LN)*x on the fly in the
//               k-loop, 3 skinny MFMAs; epilogue folds softplus/exp ->
//               {u,v} r-domain pairs + Ct; zeroes flags.
//  K5 scan+out: R4-verified FUSED kernel (~128us):
//               blocks 0..7 scan (consumer wave setprio(3), agent
//               write-through hs flush, relaxed flag publish);
//               blocks 8..519 output GEMM, 2 rows/iter, bounded spins.
//
#define M_TOK   32768
#define LNEPS   1e-5f
#define TWO_LOG2E 2.8853900817779268f   // 2/ln(2)

typedef float  f32x4 __attribute__((ext_vector_type(4)));
typedef short  s16x8 __attribute__((ext_vector_type(8)));
typedef unsigned long long ull;

__device__ __forceinline__ unsigned short f2b(float v) {
  return __builtin_bit_cast(unsigned short, __float2bfloat16(v));
}
__device__ __forceinline__ float b2f(unsigned short u) {
  return __bfloat162float(__builtin_bit_cast(__hip_bfloat16, u));
}
__device__ __forceinline__ float red64(float v) {
#pragma unroll
  for (int off = 32; off >= 1; off >>= 1) v += __shfl_xor(v, off, 64);
  return v;
}

// async global->LDS, 16B per lane. LDS dest is wave-uniform base + lane*16.
__device__ __forceinline__ void async_cp16(const void* g, void* l) {
  using gp = const __attribute__((address_space(1))) char*;
  using lp = __attribute__((address_space(3))) char*;
  __builtin_amdgcn_global_load_lds((gp)(uint64_t)g,
                                   (lp)(uint32_t)(uint64_t)l, 16, 0, 0);
}

// ---------------------------------------------------------------- K1 convert
// Grid 33904: blocks 0..33839 convert (exactly 8663040 float4s); blocks
// 33840..33903 zero the 256KB LN-stats array (16384 float4s).
__global__ __launch_bounds__(256) void k_convert(
    const float* __restrict__ x, const float* __restrict__ wg,
    const float* __restrict__ wd, const float* __restrict__ wb,
    const float* __restrict__ wc,
    unsigned short* __restrict__ Xb, unsigned short* __restrict__ Wgb,
    unsigned short* __restrict__ Wcat, float4* __restrict__ st4) {
  int i = blockIdx.x * 256 + threadIdx.x;   // one float4 per thread
  if (i >= 8663040) {                       // stats zeroing tail
    st4[i - 8663040] = (float4){0.f, 0.f, 0.f, 0.f};
    return;
  }
  const float* src;
  unsigned short* dst;
  if (i < 8388608) {                  // x: 33554432 floats
    src = x + (size_t)i * 4; dst = Xb + (size_t)i * 4;
  } else if (i < 8650752) {           // W_gate: 1048576 floats
    int j = i - 8388608;
    src = wg + (size_t)j * 4; dst = Wgb + (size_t)j * 4;
  } else {                            // Wcat = [W_delta; W_B; W_C], 49152 floats
    int j = i - 8650752;
    int e = j * 4;
    if (e < 16384)       src = wd + e;
    else if (e < 32768)  src = wb + (e - 16384);
    else                 src = wc + (e - 32768);
    dst = Wcat + e;
  }
  float4 v = *(const float4*)src;
  ushort4 o;
  o.x = f2b(v.x); o.y = f2b(v.y); o.z = f2b(v.z); o.w = f2b(v.w);
  *(ushort4*)dst = o;
}

// ------------------------------------------------------------- K2 gate GEMM
// G[m][n] = sum_k Xb[m][k] * Wgb[n][k]   (NT, both K-contiguous)
// 128x128 block tile, 4 waves in 2x2, each wave 64x64 = 4x4 MFMA 16x16x32.
// Epilogue also accumulates LN-stat partials (see header).
__global__ __launch_bounds__(256, 2) void k_gemm_gate(
    const unsigned short* __restrict__ A,   // [32768][1024] bf16
    const unsigned short* __restrict__ Bm,  // [1024][1024] bf16 (W_gate rows)
    unsigned short* __restrict__ C,         // [32768][1024] bf16
    const float* __restrict__ bg, float2* __restrict__ st) {
  __shared__ unsigned short As[128 * 32];   // 8 KB
  __shared__ unsigned short Bs[128 * 32];   // 8 KB
  const int tid  = threadIdx.x;
  const int wave = tid >> 6, lane = tid & 63;
  const int wr = wave >> 1, wc = wave & 1;
  const int lrow = lane & 15, lq = lane >> 4;
  // XCD-aware swizzle: each XCD owns 32 M-panels x all 8 N-tiles.
  const int lin  = blockIdx.y * gridDim.x + blockIdx.x;     // 0..2047
  const int unit = (lin & 7) * 256 + (lin >> 3);
  const int m0 = (unit >> 3) * 128;
  const int n0 = (unit & 7) * 128;
  const int crow  = tid >> 2;               // staging chunk row (rep 0)
  const int ccol  = (tid & 3) * 8;          // staging chunk col (elems)

  f32x4 acc[4][4];
#pragma unroll
  for (int i = 0; i < 4; i++)
#pragma unroll
    for (int j = 0; j < 4; j++) acc[i][j] = (f32x4){0.f, 0.f, 0.f, 0.f};

  for (int k0 = 0; k0 < 1024; k0 += 32) {
    async_cp16(A + (size_t)(m0 + crow) * 1024 + k0 + ccol,
               (void*)(As + (wave * 64) * 8));
    async_cp16(A + (size_t)(m0 + crow + 64) * 1024 + k0 + ccol,
               (void*)(As + (256 + wave * 64) * 8));
    async_cp16(Bm + (size_t)(n0 + crow) * 1024 + k0 + ccol,
               (void*)(Bs + (wave * 64) * 8));
    async_cp16(Bm + (size_t)(n0 + crow + 64) * 1024 + k0 + ccol,
               (void*)(Bs + (256 + wave * 64) * 8));
    __syncthreads();   // drains vmcnt (global_load_lds) before LDS reads

    s16x8 af[4], bfr[4];
#pragma unroll
    for (int i = 0; i < 4; i++)
      af[i] = *(const s16x8*)(As + (wr * 64 + i * 16 + lrow) * 32 + lq * 8);
#pragma unroll
    for (int j = 0; j < 4; j++)
      bfr[j] = *(const s16x8*)(Bs + (wc * 64 + j * 16 + lrow) * 32 + lq * 8);
#pragma unroll
    for (int i = 0; i < 4; i++)
#pragma unroll
      for (int j = 0; j < 4; j++)
        acc[i][j] = __builtin_amdgcn_mfma_f32_16x16x32_bf16(
            af[i], bfr[j], acc[i][j], 0, 0, 0);
    __syncthreads();
  }

  // C/D layout: col = lane&15, row = (lane>>4)*4 + reg
#pragma unroll
  for (int i = 0; i < 4; i++)
#pragma unroll
    for (int j = 0; j < 4; j++)
#pragma unroll
      for (int r = 0; r < 4; r++) {
        int row = m0 + wr * 64 + i * 16 + lq * 4 + r;
        int col = n0 + wc * 64 + j * 16 + lrow;
        C[(size_t)row * 1024 + col] = f2b(acc[i][j][r]);
      }

  // ---- LN-stat partials: v = G_f32 + bg over this wave's 64-col slice.
  // Reduce over lrow (16-lane groups), 2 atomicAdds per row from lrow==0.
  float bgj[4];
#pragma unroll
  for (int j = 0; j < 4; j++) bgj[j] = bg[n0 + wc * 64 + j * 16 + lrow];
#pragma unroll
  for (int i = 0; i < 4; i++)
#pragma unroll
    for (int r = 0; r < 4; r++) {
      float sv = 0.f, sq = 0.f;
#pragma unroll
      for (int j = 0; j < 4; j++) {
        float v = acc[i][j][r] + bgj[j];
        sv += v; sq = fmaf(v, v, sq);
      }
#pragma unroll
      for (int off = 1; off <= 8; off <<= 1) {
        sv += __shfl_xor(sv, off, 64);
        sq += __shfl_xor(sq, off, 64);
      }
      if (lrow == 0) {
        int row = m0 + wr * 64 + i * 16 + lq * 4 + r;
        atomicAdd(&st[row].x, sv);
        atomicAdd(&st[row].y, sq);
      }
    }
}

// ------------------------------------------------------- K34 LN+gate+proj
// 32-row tiles, 128 threads (2 waves), 1024 blocks. Stats from K2 (no
// phase 1). k-loop computes xg = sigmoid(LN(G+bg))*x on the fly (rounded
// to bf16 exactly like the old K3 path), 3 skinny MFMAs vs Wcat.
// Epilogue: {u = A2+B2, v = -2*A2} pairs + Ct flat; zeroes flags.
__global__ __launch_bounds__(128) void k_lnproj(
    const unsigned short* __restrict__ G,   // [32768][1024] bf16
    const float* __restrict__ x,
    const float* __restrict__ bgp, const float* __restrict__ lnw,
    const float* __restrict__ lnb,
    const unsigned short* __restrict__ Wcat,
    const float* __restrict__ A_diag, const float2* __restrict__ st,
    float* __restrict__ UV, float* __restrict__ Ct, int* __restrict__ flags) {
  __shared__ unsigned short As[32 * 32];   // 2 KB (xg tile bf16)
  __shared__ unsigned short Bs[48 * 32];   // 3 KB (Wcat tile)
  const int tid  = threadIdx.x;
  const int wave = tid >> 6, lane = tid & 63;
  const int lrow = lane & 15, lq = lane >> 4;
  const int r0 = blockIdx.x * 32;
  const int crow = tid >> 2, ccol = (tid & 3) * 8;

  if (blockIdx.x == 0 && tid < 8)
    __hip_atomic_store(&flags[tid], 0, __ATOMIC_RELAXED,
                       __HIP_MEMORY_SCOPE_AGENT);   // write-through zeroing

  // per-thread LN stats for the staging row
  float2 s2 = st[r0 + crow];
  const float mu = s2.x * (1.0f / 1024.0f);
  const float var = s2.y * (1.0f / 1024.0f) - mu * mu;
  const float rs = rsqrtf(var + LNEPS);

  f32x4 acc[3];
#pragma unroll
  for (int j = 0; j < 3; j++) acc[j] = (f32x4){0.f, 0.f, 0.f, 0.f};

  for (int k0 = 0; k0 < 1024; k0 += 32) {
    s16x8 gv = *(const s16x8*)(G + (size_t)(r0 + crow) * 1024 + k0 + ccol);
    float xs[8], bgs[8], lws[8], lbs[8];
    *(float4*)&xs[0]  = *(const float4*)(x   + (size_t)(r0 + crow) * 1024 + k0 + ccol);
    *(float4*)&xs[4]  = *(const float4*)(x   + (size_t)(r0 + crow) * 1024 + k0 + ccol + 4);
    *(float4*)&bgs[0] = *(const float4*)(bgp + k0 + ccol);
    *(float4*)&bgs[4] = *(const float4*)(bgp + k0 + ccol + 4);
    *(float4*)&lws[0] = *(const float4*)(lnw + k0 + ccol);
    *(float4*)&lws[4] = *(const float4*)(lnw + k0 + ccol + 4);
    *(float4*)&lbs[0] = *(const float4*)(lnb + k0 + ccol);
    *(float4*)&lbs[4] = *(const float4*)(lnb + k0 + ccol + 4);
    uint4 bv0 = *(const uint4*)(Wcat + (size_t)crow * 1024 + k0 + ccol);
    uint4 bv1;
    if (tid < 64)
      bv1 = *(const uint4*)(Wcat + (size_t)(32 + (tid >> 2)) * 1024 + k0 + ccol);
    __syncthreads();                       // prev iter done reading LDS
    // xg = sigmoid((v-mu)*rs*lnw + lnb) * x, rounded to bf16 (as old K3)
    s16x8 ov;
#pragma unroll
    for (int i = 0; i < 8; i++) {
      float v = b2f((unsigned short)gv[i]) + bgs[i];
      float u = (v - mu) * rs * lws[i] + lbs[i];
      float g = 1.0f / (1.0f + __expf(-u));
      ov[i] = (short)f2b(g * xs[i]);
    }
    *(s16x8*)(As + crow * 32 + ccol) = ov;
    *(uint4*)(Bs + crow * 32 + ccol) = bv0;
    if (tid < 64) *(uint4*)(Bs + (32 + (tid >> 2)) * 32 + ccol) = bv1;
    __syncthreads();
    s16x8 af = *(const s16x8*)(As + (wave * 16 + lrow) * 32 + lq * 8);
#pragma unroll
    for (int j = 0; j < 3; j++) {
      s16x8 bf8 = *(const s16x8*)(Bs + (j * 16 + lrow) * 32 + lq * 8);
      acc[j] = __builtin_amdgcn_mfma_f32_16x16x32_bf16(af, bf8, acc[j], 0, 0, 0);
    }
  }

  float ad = A_diag[lrow];
#pragma unroll
  for (int r = 0; r < 4; r++) {
    int row = r0 + wave * 16 + lq * 4 + r;
    float z  = acc[0][r];
    float sp = fmaxf(z, 0.0f) + log1pf(__expf(-fabsf(z)));  // softplus
    float A2 = __expf(sp * ad) * TWO_LOG2E;                  // A_bar scaled
    float B2 = acc[1][r] * TWO_LOG2E;
    float2 o;
    o.x = A2 + B2;          // u
    o.y = -2.0f * A2;       // v
    *(float2*)(UV + (size_t)row * 32 + lrow * 2) = o;
    Ct[(size_t)row * 16 + lrow] = acc[2][r];
  }
}

// --------------------------------------------------------- K5 scan + output
#define TC 128                // steps per chunk
#define NCH (4096 / TC)       // 32 chunks
#define NOUT 512              // output blocks; 1024 rows/chunk = 2 per block

__device__ __forceinline__ void load16(float2 (&P)[16], const float* uvb,
                                       int j, int lane) {
#pragma unroll
  for (int i = 0; i < 16; ++i)
    P[i] = *(const float2*)(uvb + ((j * 16 + i) * 16 + lane) * 2);
}
__device__ __forceinline__ void fast16(float2 (&P)[16], float& r, float& h,
                                       float* hhb, int j, int lane) {
#pragma unroll
  for (int i = 0; i < 16; ++i) {
    float w = fmaf(P[i].y, r, P[i].x);
    float e = __builtin_amdgcn_exp2f(w);
    r = __builtin_amdgcn_rcpf(e + 1.0f);
    h = fmaf(-2.0f, r, 1.0f);
    hhb[(j * 16 + i) * 16 + lane] = h;
  }
}
__device__ __forceinline__ void slow16(float2 (&P)[16], float& h,
                                       const float* mb, float* hhb,
                                       int j, int lane) {
#pragma unroll
  for (int i = 0; i < 16; ++i) {
    float v  = P[i].y, u = P[i].x;
    float A2 = -0.5f * v;
    float B2 = fmaf(0.5f, v, u);
    float w  = fmaf(A2, h, B2);
    float e  = __builtin_amdgcn_exp2f(w);
    float rr = __builtin_amdgcn_rcpf(e + 1.0f);
    float th = fmaf(-2.0f, rr, 1.0f);
    float m  = mb[j * 16 + i];
    h = fmaf(m, th - h, h);
    hhb[(j * 16 + i) * 16 + lane] = h;
  }
}

__global__ __launch_bounds__(512, 6) void k_scan_out(
    const float* __restrict__ UV, const float* __restrict__ mask,
    const float* __restrict__ h0, float* __restrict__ hs,
    float* __restrict__ hfin,
    const float* __restrict__ Ct, const float* __restrict__ x,
    const float* __restrict__ Wout, const float* __restrict__ Dd,
    float* __restrict__ y, int* __restrict__ flags) {
  __shared__ float uvL[2][TC * 32];    // 2 x 16 KB
  __shared__ float hhL[2][TC * 16];    // 2 x 8 KB
  __shared__ float mskL[2][TC];        // 2 x 512 B

  const int tid = threadIdx.x;

  if (blockIdx.x >= 8) {
    // ============================ OUTPUT ROLE ============================
    const int o    = blockIdx.x - 8;          // 0..511
    const int wv   = tid >> 6;
    const int lane = tid & 63;
    const int d0   = wv * 128 + lane * 2;
    const int b0   = o >> 7;                  // 0..3
    const int b1   = b0 + 4;                  // 4..7
    const int j0   = o & 127;

    float wa[16], wb[16];
#pragma unroll
    for (int q = 0; q < 4; q++) {
      *(float4*)&wa[q * 4] = *(const float4*)(Wout + (size_t)d0 * 16 + q * 4);
      *(float4*)&wb[q * 4] = *(const float4*)(Wout + (size_t)(d0 + 1) * 16 + q * 4);
    }
    float2 D2 = *(const float2*)(Dd + d0);

    for (int c = 0; c < NCH; ++c) {
      size_t r0 = (size_t)b0 * 4096 + (size_t)c * TC + j0;
      size_t r1 = (size_t)b1 * 4096 + (size_t)c * TC + j0;
      int spins = 0;
      for (;;) {
        int f = 0;
        if (lane == 0) {
          int fa = __hip_atomic_load(&flags[b0], __ATOMIC_RELAXED,
                                     __HIP_MEMORY_SCOPE_AGENT);
          int fb = __hip_atomic_load(&flags[b1], __ATOMIC_RELAXED,
                                     __HIP_MEMORY_SCOPE_AGENT);
          f = (fa < fb) ? fa : fb;
        }
        f = __shfl(f, 0);
        if (f > c || spins > (1 << 18)) break;
        ++spins;
        __builtin_amdgcn_s_sleep(32);
      }
      float cv0 = Ct[r0 * 16 + (lane & 15)];
      float cv1 = Ct[r1 * 16 + (lane & 15)];
      float hv0 = __hip_atomic_load(&hs[r0 * 16 + (lane & 15)],
                                    __ATOMIC_RELAXED, __HIP_MEMORY_SCOPE_AGENT);
      float hv1 = __hip_atomic_load(&hs[r1 * 16 + (lane & 15)],
                                    __ATOMIC_RELAXED, __HIP_MEMORY_SCOPE_AGENT);
      float2 x20 = *(const float2*)(x + r0 * 1024 + d0);
      float2 x21 = *(const float2*)(x + r1 * 1024 + d0);
      float sv0 = cv0 * hv0;
      float sv1 = cv1 * hv1;
      float a0x = D2.x * x20.x, a0y = D2.y * x20.y;
      float a1x = D2.x * x21.x, a1y = D2.y * x21.y;
#pragma unroll
      for (int s = 0; s < 16; s++) {
        float s0 = __shfl(sv0, s);
        float s1 = __shfl(sv1, s);
        a0x = fmaf(wa[s], s0, a0x);
        a0y = fmaf(wb[s], s0, a0y);
        a1x = fmaf(wa[s], s1, a1x);
        a1y = fmaf(wb[s], s1, a1y);
      }
      float2 o0; o0.x = a0x; o0.y = a0y;
      float2 o1; o1.x = a1x; o1.y = a1y;
      *(float2*)(y + r0 * 1024 + d0) = o0;
      *(float2*)(y + r1 * 1024 + d0) = o1;
    }
    return;
  }

  // ============================== SCAN ROLE ==============================
  const int b   = blockIdx.x;
  const float* pm = mask + (size_t)b * 4096;
  const size_t uvbase = (size_t)b * 4096 * 32;   // floats
  const size_t hsbase = (size_t)b * 4096 * 16;   // floats

  if (tid < 64) __builtin_amdgcn_s_setprio(3);   // critical recurrence wave

  float h = 0.f, r = 0.f;
  if (tid < 16) {
    h = h0[b * 16 + tid];
    r = 0.5f - 0.5f * h;        // invariant r = (1-h)/2
  }

  // ---- priming: load chunk 0 (UV + mask)
  if (tid >= 64) {
    int pt = tid - 64;                          // 0..447
    const uint4* src = (const uint4*)(UV + uvbase);
    for (int i = pt; i < TC * 8; i += 448) ((uint4*)uvL[0])[i] = src[i];
    if (tid < 128) {
      int l = tid - 64;
      mskL[0][l]      = pm[l];
      mskL[0][l + 64] = pm[l + 64];
    }
  }
  __syncthreads();

  for (int c = 0; c < NCH; ++c) {
    // publish chunks 0..c-2: their agent write-through stores were drained
    // by iteration c-1's pre-barrier vmcnt(0); relaxed store suffices.
    if (c >= 2 && tid == 511) {
      __hip_atomic_store(&flags[b], c - 1, __ATOMIC_RELAXED,
                         __HIP_MEMORY_SCOPE_AGENT);
    }
    const int p = c & 1;
    if (tid < 64) {
      // ---------------- consumer wave
      const int lane = tid;
      float mv0 = mskL[p][2 * lane], mv1 = mskL[p][2 * lane + 1];
      bool on = (mv0 == 1.0f) && (mv1 == 1.0f);
      bool allones = (__ballot(on) == 0xFFFFFFFFFFFFFFFFull);
      if (lane < 16) {
        const float* uvb = uvL[p];
        float* hhb = hhL[p];
        float2 Pa[16], Pb[16];
        load16(Pa, uvb, 0, lane);
        if (allones) {
#pragma unroll
          for (int j = 0; j < 8; j += 2) {
            load16(Pb, uvb, j + 1, lane);
            fast16(Pa, r, h, hhb, j, lane);
            if (j + 2 < 8) load16(Pa, uvb, j + 2, lane);
            fast16(Pb, r, h, hhb, j + 1, lane);
          }
        } else {
#pragma unroll
          for (int j = 0; j < 8; j += 2) {
            load16(Pb, uvb, j + 1, lane);
            slow16(Pa, h, mskL[p], hhb, j, lane);
            if (j + 2 < 8) load16(Pa, uvb, j + 2, lane);
            slow16(Pb, h, mskL[p], hhb, j + 1, lane);
          }
          r = 0.5f - 0.5f * h;
        }
      }
    } else {
      // ---------------- producer waves 1..7
      int pt = tid - 64;                        // 0..447
      if (c + 1 < NCH) {
        const uint4* src =
            (const uint4*)(UV + uvbase + (size_t)(c + 1) * TC * 32);
        uint4* dst = (uint4*)uvL[(c + 1) & 1];
        for (int i = pt; i < TC * 8; i += 448) dst[i] = src[i];
        if (tid < 128) {
          int l = tid - 64;
          mskL[(c + 1) & 1][l]      = pm[(c + 1) * TC + l];
          mskL[(c + 1) & 1][l + 64] = pm[(c + 1) * TC + l + 64];
        }
      }
      if (c > 0) {
        // flush chunk c-1 h-history: agent write-through 8B stores
        const ull* s2 = (const ull*)hhL[(c - 1) & 1];
        ull* d2 = (ull*)(hs + hsbase + (size_t)(c - 1) * TC * 16);
        for (int i = pt; i < TC * 8; i += 448)
          __hip_atomic_store(&d2[i], s2[i], __ATOMIC_RELAXED,
                             __HIP_MEMORY_SCOPE_AGENT);
      }
    }
    __syncthreads();
  }

  // ---- epilogue: store last chunk's h-history
  {
    const ull* s2 = (const ull*)hhL[(NCH - 1) & 1];
    ull* d2 = (ull*)(hs + hsbase + (size_t)(NCH - 1) * TC * 16);
    for (int i = tid; i < TC * 8; i += 512)
      __hip_atomic_store(&d2[i], s2[i], __ATOMIC_RELAXED,
                         __HIP_MEMORY_SCOPE_AGENT);
  }
  __syncthreads();                              // drains vmcnt: epi + ch30 flush
  if (tid == 511) {
    __hip_atomic_store(&flags[b], NCH, __ATOMIC_RELAXED,
                       __HIP_MEMORY_SCOPE_AGENT);
  }
  if (tid < 16) hfin[b * 16 + tid] = h;
}

// ---------------------------------------------------------------- launcher
extern "C" void kernel_launch(void* const* d_in, const int* in_sizes, int n_in,
                              void* d_out, int out_size, void* d_ws, size_t ws_size,
                              hipStream_t stream) {
  const float* x       = (const float*)d_in[0];
  const float* h0      = (const float*)d_in[1];
  const float* mask    = (const float*)d_in[2];
  const float* A_diag  = (const float*)d_in[3];
  const float* W_delta = (const float*)d_in[4];
  const float* W_B     = (const float*)d_in[5];
  const float* W_C     = (const float*)d_in[6];
  const float* W_out   = (const float*)d_in[7];
  const float* Dd      = (const float*)d_in[8];
  const float* W_gate  = (const float*)d_in[9];
  const float* b_gate  = (const float*)d_in[10];
  const float* ln_w    = (const float*)d_in[11];
  const float* ln_b    = (const float*)d_in[12];

  char* ws = (char*)d_ws;
  unsigned short* Xb   = (unsigned short*)(ws);               // 64 MB
  unsigned short* Gb   = (unsigned short*)(ws + 67108864);    // 64 MB
  unsigned short* Wgb  = (unsigned short*)(ws + 134217728);   // 2 MB
  unsigned short* Wcat = (unsigned short*)(ws + 136314880);   // 96 KB of 128 KB slot
  int* flags = (int*)(ws + 136413184);                        // 32 B, in pad gap
  float* UVb = (float*)(ws + 136445952);                      // 4 MB {u,v}
  float* Ctb = (float*)(ws + 140640256);                      // 2 MB
  float* hsb = (float*)(ws + 142737408);                      // 2 MB (end 144834560, verified footprint)
  // LN stats alias the first 256KB of hsb: written by K2 (after K1 zeroes),
  // read by k_lnproj, then dead -- scan overwrites the region afterwards.
  float2* stats = (float2*)hsb;

  float* y    = (float*)d_out;
  float* hfin = y + 33554432;

  hipLaunchKernelGGL(k_convert, dim3(33904), dim3(256), 0, stream,
                     x, W_gate, W_delta, W_B, W_C, Xb, Wgb, Wcat,
                     (float4*)stats);
  hipLaunchKernelGGL(k_gemm_gate, dim3(256, 8), dim3(256), 0, stream,
                     Xb, Wgb, Gb, b_gate, stats);
  hipLaunchKernelGGL(k_lnproj, dim3(1024), dim3(128), 0, stream,
                     Gb, x, b_gate, ln_w, ln_b, Wcat, A_diag, stats,
                     UVb, Ctb, flags);
  hipLaunchKernelGGL(k_scan_out, dim3(8 + NOUT), dim3(512), 0, stream,
                     UVb, mask, h0, hsb, hfin, Ctb, x, W_out, Dd, y, flags);
}